// Round 18
// baseline (72.687 us; speedup 1.0000x reference)
//
#include <hip/hip_runtime.h>
#include <math.h>

#define NB 8192
#define ND 512
#define NPROTO 16
#define NBLK 256                   // k_norm grid
#define TINV 14.285714285714286f   // 1/0.07
#define PW_BLOCKS 128
#define PL_BLOCKS 256
#define FIN_BLOCKS 64

typedef short short8 __attribute__((ext_vector_type(8)));
typedef float float4v __attribute__((ext_vector_type(4)));

__device__ __forceinline__ unsigned short f2bf(float f) {
  unsigned u = __builtin_bit_cast(unsigned, f);
  unsigned r = (u + 0x7FFFu + ((u >> 16) & 1u)) >> 16;
  return (unsigned short)r;
}
__device__ __forceinline__ float bflo(unsigned u) {
  return __builtin_bit_cast(float, u << 16);
}
__device__ __forceinline__ float bfhi(unsigned u) {
  return __builtin_bit_cast(float, u & 0xFFFF0000u);
}

// ---- K1: wave-per-row normalize + bf16 store + non-atomic partial sums ----
__global__ __launch_bounds__(512) void k_norm(
    const float* __restrict__ z, const float* __restrict__ attr,
    unsigned short* __restrict__ znb, float* __restrict__ partialSum,
    int* __restrict__ code, unsigned* __restrict__ doneCnt)
{
  __shared__ float acc[NPROTO * ND];   // 32 KB
  const int t = threadIdx.x, lane = t & 63, wid = t >> 6;
  for (int i = t; i < NPROTO * ND; i += 512) acc[i] = 0.f;
  if (blockIdx.x == 0 && t == 0) doneCnt[0] = 0u;   // re-arm finalize each replay
  __syncthreads();
  #pragma unroll
  for (int rr = 0; rr < 4; ++rr) {
    const int r = blockIdx.x * 32 + wid * 4 + rr;
    const float4* zr4 = (const float4*)(z + (size_t)r * ND);
    const float4 va = zr4[lane];
    const float4 vb = zr4[lane + 64];
    float v[8] = {va.x, va.y, va.z, va.w, vb.x, vb.y, vb.z, vb.w};
    float s = 0.f;
    #pragma unroll
    for (int k = 0; k < 8; ++k) s += v[k] * v[k];
    #pragma unroll
    for (int o = 32; o > 0; o >>= 1) s += __shfl_xor(s, o);
    const float inv = 1.f / fmaxf(sqrtf(s), 1e-12f);
    const float* a = attr + (size_t)r * 4;
    const int c = (a[0] > 0.5f ? 8 : 0) | (a[1] > 0.5f ? 4 : 0) |
                  (a[2] > 0.5f ? 2 : 0) | (a[3] > 0.5f ? 1 : 0);
    float* accRow = acc + c * ND;
    #pragma unroll
    for (int k = 0; k < 8; ++k) {
      const float zv = v[k] * inv;
      atomicAdd(&accRow[k * 64 + lane], zv);         // bank=lane%32: conflict-free
      znb[(size_t)r * ND + k * 64 + lane] = f2bf(zv);
    }
    if (lane == 0) code[r] = c;
  }
  __syncthreads();
  for (int i = t; i < NPROTO * ND; i += 512) {      // full overwrite: no pre-zero
    const int p = i >> 9, d = i & 511;
    partialSum[(size_t)((p << 8) | blockIdx.x) * ND + d] = acc[i];
  }
}

// ---- K1b: stage-1 reduce: 256 blocks, (p,c) sums 16 partials --------------
__global__ __launch_bounds__(256) void k_reduce1(
    const float* __restrict__ partialSum, float* __restrict__ partial2)
{
  const int t = threadIdx.x;
  const int p = blockIdx.x >> 4, c = blockIdx.x & 15;
  const float* base = partialSum + (size_t)(p * NBLK + c * 16) * ND;
  float s0 = 0.f, s1 = 0.f;
  #pragma unroll
  for (int k = 0; k < 16; ++k) {
    s0 += base[k * ND + t];
    s1 += base[k * ND + t + 256];
  }
  partial2[(size_t)(p * 16 + c) * ND + t] = s0;
  partial2[(size_t)(p * 16 + c) * ND + t + 256] = s1;
}

// ---- K2: 16 blocks: final reduce (32KB each) + normalize + validList ------
__global__ __launch_bounds__(512) void k_protonorm(
    const float* __restrict__ partial2, const int* __restrict__ code,
    float* __restrict__ protos, int* __restrict__ validList,
    int* __restrict__ validCnt)
{
  __shared__ float red[8];
  __shared__ int lcnt;
  const int t = threadIdx.x, lane = t & 63, wid = t >> 6;
  const int p = blockIdx.x;
  if (t == 0) lcnt = 0;
  __syncthreads();
  const float* base = partial2 + (size_t)p * 16 * ND;
  float s = 0.f;
  #pragma unroll
  for (int c = 0; c < 16; ++c)
    s += base[c * ND + t];
  float cl = 0.f;
  for (int r = t; r < NB; r += 512) {
    const int match = (code[r] == p) ? 1 : 0;
    cl += (float)match;
    if (p == NPROTO - 1 && match) {
      const int slot = atomicAdd(&lcnt, 1);
      validList[slot] = r;
    }
  }
  #pragma unroll
  for (int o = 32; o > 0; o >>= 1) cl += __shfl_xor(cl, o);
  if (lane == 0) red[wid] = cl;
  __syncthreads();
  const float cTot = red[0]+red[1]+red[2]+red[3]+red[4]+red[5]+red[6]+red[7];
  __syncthreads();
  const float mean = s / fmaxf(cTot, 1.f);
  float sq = mean * mean;
  #pragma unroll
  for (int o = 32; o > 0; o >>= 1) sq += __shfl_xor(sq, o);
  if (lane == 0) red[wid] = sq;
  __syncthreads();
  const float sum = red[0]+red[1]+red[2]+red[3]+red[4]+red[5]+red[6]+red[7];
  const float scale = (cTot > 0.f) ? 1.f / fmaxf(sqrtf(sum), 1e-12f) : 0.f;
  protos[p * ND + t] = mean * scale;
  if (p == NPROTO - 1 && t == 0) validCnt[0] = lcnt;
}

// ---- K3: fused {pairwise MFMA GEMM (512thr, 128x256 tile) | protoloss} ----
#define PLD (ND + 4)
#define SMEM_BYTES 50048
__global__ __launch_bounds__(512) void k_main(
    const unsigned short* __restrict__ znb, const float* __restrict__ protos,
    const int* __restrict__ code, const int* __restrict__ validList,
    const int* __restrict__ validCnt,
    float* __restrict__ partialAll, float* __restrict__ partialPos,
    float* __restrict__ plPart)
{
  __shared__ __align__(16) char smem[SMEM_BYTES];
  __shared__ float red3[8];
  const int t = threadIdx.x, lane = t & 63, wid = t >> 6;
  const int bi = blockIdx.x;
  if (bi < PW_BLOCKS) {
    // ---- pairwise: 8 waves (2i x 4j), tile 128i x 256j, K-chunk 64 -------
    unsigned short* aT = (unsigned short*)smem;             // 128x64, 16 KB
    unsigned short* bT = aT + 128 * 64;                     // 256x64, 32 KB
    int* rowIdx = (int*)(bT + 256 * 64);                    // 128
    unsigned char* aoSh = (unsigned char*)(rowIdx + 128);   // 256
    const int wv = wid >> 2, ww = wid & 3;
    const int m = validCnt[0];
    const int nIT = (m + 127) >> 7;                         // i-tiles of 128
    const int items = nIT * 32;                             // 32 j-tiles of 256
    const int grp = lane >> 4, cl = lane & 15;
    for (int wi = bi; wi < items; wi += PW_BLOCKS) {
      const int i0 = (wi >> 5) * 128;
      const int jt = wi & 31;
      const int jb = jt * 256;
      __syncthreads();
      if (t < 128) rowIdx[t] = (i0 + t < m) ? validList[i0 + t] : -1;
      if (t < 256) aoSh[t] = (code[jb + t] == NPROTO - 1) ? 1 : 0;
      float4v acc[4][4];
      #pragma unroll
      for (int mi = 0; mi < 4; ++mi)
        #pragma unroll
        for (int nj = 0; nj < 4; ++nj) acc[mi][nj] = (float4v)(0.f);
      for (int kc = 0; kc < 8; ++kc) {
        const int k0 = kc * 64;
        __syncthreads();
        #pragma unroll
        for (int h = 0; h < 2; ++h) {  // stage A: 128 rows x 8 chunks, 2/thread
          const int f = t + h * 512;
          const int ia = f >> 3, kq = f & 7;
          const int ri = rowIdx[ia];
          const int srow = (ri < 0) ? 0 : ri;
          const uint4 v = *(const uint4*)(znb + (size_t)srow * ND + k0 + kq * 8);
          *(uint4*)((char*)aT + ia * 128 + ((kq * 16) ^ ((ia & 7) << 4))) = v;
        }
        #pragma unroll
        for (int h = 0; h < 4; ++h) {  // stage B: 256 rows x 8 chunks, 4/thread
          const int f = t + h * 512;
          const int j = f >> 3, kq = f & 7;
          const uint4 v = *(const uint4*)(znb + (size_t)(jb + j) * ND + k0 + kq * 8);
          *(uint4*)((char*)bT + j * 128 + ((kq * 16) ^ ((j & 7) << 4))) = v;
        }
        __syncthreads();
        #pragma unroll
        for (int ks = 0; ks < 2; ++ks) {
          const int kb = ks * 64 + grp * 16;
          short8 bf[4];
          #pragma unroll
          for (int nj = 0; nj < 4; ++nj) {
            const int rw = ww * 64 + nj * 16 + cl;
            bf[nj] = *(const short8*)((char*)bT + rw * 128 + (kb ^ ((rw & 7) << 4)));
          }
          #pragma unroll
          for (int mi = 0; mi < 4; ++mi) {
            const int rw = wv * 64 + mi * 16 + cl;
            const short8 af = *(const short8*)((char*)aT + rw * 128 + (kb ^ ((rw & 7) << 4)));
            #pragma unroll
            for (int nj = 0; nj < 4; ++nj)
              acc[mi][nj] = __builtin_amdgcn_mfma_f32_16x16x32_bf16(af, bf[nj], acc[mi][nj], 0, 0, 0);
          }
        }
      }
      // epilogue: exp, diag+pos masks, row sums, direct partial writes
      #pragma unroll
      for (int mi = 0; mi < 4; ++mi) {
        float sA[4] = {0.f, 0.f, 0.f, 0.f}, sP[4] = {0.f, 0.f, 0.f, 0.f};
        int ri[4];
        #pragma unroll
        for (int q = 0; q < 4; ++q) ri[q] = rowIdx[wv * 64 + mi * 16 + grp * 4 + q];
        #pragma unroll
        for (int nj = 0; nj < 4; ++nj) {
          const int jl = ww * 64 + nj * 16 + cl;
          const int jg = jb + jl;
          const float ao = aoSh[jl] ? 1.f : 0.f;
          #pragma unroll
          for (int q = 0; q < 4; ++q) {
            float e = __expf(acc[mi][nj][q] * TINV);
            e = (jg == ri[q]) ? 0.f : e;
            sA[q] += e;
            sP[q] += e * ao;
          }
        }
        #pragma unroll
        for (int q = 0; q < 4; ++q) {
          #pragma unroll
          for (int o = 1; o < 16; o <<= 1) {
            sA[q] += __shfl_xor(sA[q], o);
            sP[q] += __shfl_xor(sP[q], o);
          }
        }
        if (cl == 0) {
          const int slot0 = i0 + wv * 64 + mi * 16 + grp * 4;
          const int jt2 = jt * 4 + ww;                      // 0..127
          if (slot0 + 3 < m) {
            *(float4*)&partialAll[(size_t)jt2 * NB + slot0] =
                make_float4(sA[0], sA[1], sA[2], sA[3]);
            *(float4*)&partialPos[(size_t)jt2 * NB + slot0] =
                make_float4(sP[0], sP[1], sP[2], sP[3]);
          } else {
            #pragma unroll
            for (int q = 0; q < 4; ++q) {
              if (slot0 + q < m) {
                partialAll[(size_t)jt2 * NB + slot0 + q] = sA[q];
                partialPos[(size_t)jt2 * NB + slot0 + q] = sP[q];
              }
            }
          }
        }
      }
    }
  } else {
    // -------- protoloss: 256 blocks x 512 thr, 32 rows each ---------------
    float* pl = (float*)smem;                               // [16][PLD]
    const int pb = bi - PW_BLOCKS;
    for (int i = t; i < NPROTO * ND; i += 512)
      pl[(i >> 9) * PLD + (i & 511)] = protos[i];
    __syncthreads();
    const int p = lane & 15, grp = lane >> 4;
    float lacc = 0.f;
    #pragma unroll
    for (int rr = 0; rr < 4; ++rr) {
      const int r = pb * 32 + wid * 4 + rr;
      const uint4* zr = (const uint4*)(znb + (size_t)r * ND + grp * 128);
      const float* pbp = &pl[p * PLD + grp * 128];
      float s = 0.f;
      #pragma unroll
      for (int it = 0; it < 16; ++it) {
        const uint4 u = zr[it];
        const float4 p0 = *(const float4*)(pbp + it * 8);
        const float4 p1 = *(const float4*)(pbp + it * 8 + 4);
        s += bflo(u.x)*p0.x + bfhi(u.x)*p0.y + bflo(u.y)*p0.z + bfhi(u.y)*p0.w;
        s += bflo(u.z)*p1.x + bfhi(u.z)*p1.y + bflo(u.w)*p1.z + bfhi(u.w)*p1.w;
      }
      s += __shfl_xor(s, 16);
      s += __shfl_xor(s, 32);
      const float e = __expf(s * TINV);
      float alls = e;
      alls += __shfl_xor(alls, 1);
      alls += __shfl_xor(alls, 2);
      alls += __shfl_xor(alls, 4);
      alls += __shfl_xor(alls, 8);
      const int c = code[r];
      const float pos = __shfl(e, (lane & ~15) | c);
      if (lane == 0) lacc += -logf(pos / fmaxf(alls, 1e-8f) + 1e-8f);
    }
    if (lane == 0) red3[wid] = lacc;
    __syncthreads();
    if (t == 0)
      plPart[pb] = red3[0]+red3[1]+red3[2]+red3[3]+red3[4]+red3[5]+red3[6]+red3[7];
  }
}

// ---- K4: finalize v2 — 64 blocks, wave-per-slot coalesced column reduce,
//          completion-counter final combine ---------------------------------
__global__ __launch_bounds__(512) void k_final(
    const float* __restrict__ partialAll, const float* __restrict__ partialPos,
    const float* __restrict__ plPart, const int* __restrict__ validCnt,
    float* __restrict__ blockLoss, unsigned* __restrict__ doneCnt,
    float* __restrict__ out)
{
  __shared__ float red[8], red2[8];
  __shared__ bool isLast;
  const int t = threadIdx.x, lane = t & 63, wid = t >> 6;
  const int bi = blockIdx.x;
  const int m = validCnt[0];
  const int nvalid = (m >= 2) ? m : 0;
  float bl = 0.f;
  for (int s = bi * 8 + wid; s < nvalid; s += FIN_BLOCKS * 8) {
    float a = partialAll[(size_t)lane * NB + s] +
              partialAll[(size_t)(lane + 64) * NB + s];
    float p = partialPos[(size_t)lane * NB + s] +
              partialPos[(size_t)(lane + 64) * NB + s];
    #pragma unroll
    for (int o = 32; o > 0; o >>= 1) {
      a += __shfl_xor(a, o);
      p += __shfl_xor(p, o);
    }
    if (lane == 0) bl += -logf(p / (a + 1e-8f) + 1e-8f);
  }
  if (lane == 0) red[wid] = bl;
  __syncthreads();
  if (t == 0) {
    blockLoss[bi] = red[0]+red[1]+red[2]+red[3]+red[4]+red[5]+red[6]+red[7];
    __threadfence();
    const unsigned v = atomicAdd(doneCnt, 1u);
    isLast = (v == (unsigned)(FIN_BLOCKS - 1));
  }
  __syncthreads();
  if (!isLast) return;
  __threadfence();
  float s = (t < FIN_BLOCKS) ? atomicAdd(&blockLoss[t], 0.f) : 0.f;
  float pls = (t < PL_BLOCKS) ? plPart[t] : 0.f;
  #pragma unroll
  for (int o = 32; o > 0; o >>= 1) {
    s += __shfl_xor(s, o);
    pls += __shfl_xor(pls, o);
  }
  if (lane == 0) { red[wid] = s; red2[wid] = pls; }
  __syncthreads();
  if (t == 0) {
    const float total = red[0]+red[1]+red[2]+red[3]+red[4]+red[5]+red[6]+red[7];
    const float plTot = red2[0]+red2[1]+red2[2]+red2[3]+red2[4]+red2[5]+red2[6]+red2[7];
    const float proto = plTot / (float)NB;
    float loss = proto;
    if (nvalid > 0) loss = 0.7f * proto + 0.3f * (total / (float)nvalid);
    out[0] = loss;
  }
}

extern "C" void kernel_launch(void* const* d_in, const int* in_sizes, int n_in,
                              void* d_out, int out_size, void* d_ws, size_t ws_size,
                              hipStream_t stream) {
  const float* z = (const float*)d_in[0];
  const float* attr = (const float*)d_in[1];
  unsigned short* znb = (unsigned short*)d_ws;            // NB*ND bf16 (8 MB)
  float* partialSum = (float*)(znb + (size_t)NB * ND);    // [p][b][d] (8 MB)
  // overlay: partialSum is dead after k_reduce1/protonorm; k_main reuses it
  float* partialAll = partialSum;                         // [128][NB] (4 MB)
  float* partialPos = partialSum + (size_t)128 * NB;      // [128][NB] (4 MB)
  char* w = (char*)(partialSum + (size_t)NBLK * NPROTO * ND);
  float* partial2 = (float*)w;      w += (size_t)NPROTO * 16 * ND * 4;  // 512 KB
  int* validCnt = (int*)w;          w += 16;
  int* code = (int*)w;              w += NB * 4;
  int* validList = (int*)w;         w += NB * 4;
  float* protos = (float*)w;        w += NPROTO * ND * 4;
  float* plPart = (float*)w;        w += PL_BLOCKS * 4;
  float* blockLoss = (float*)w;     w += FIN_BLOCKS * 4;
  unsigned* doneCnt = (unsigned*)w; w += 16;
  k_norm<<<dim3(NBLK), dim3(512), 0, stream>>>(z, attr, znb, partialSum, code,
                                               doneCnt);
  k_reduce1<<<dim3(256), dim3(256), 0, stream>>>(partialSum, partial2);
  k_protonorm<<<dim3(NPROTO), dim3(512), 0, stream>>>(partial2, code, protos,
                                                      validList, validCnt);
  k_main<<<dim3(PW_BLOCKS + PL_BLOCKS), dim3(512), 0, stream>>>(
      znb, protos, code, validList, validCnt, partialAll, partialPos, plPart);
  k_final<<<dim3(FIN_BLOCKS), dim3(512), 0, stream>>>(
      partialAll, partialPos, plPart, validCnt, blockLoss, doneCnt,
      (float*)d_out);
}

// Round 19
// 66.603 us; speedup vs baseline: 1.0914x; 1.0914x over previous
//
#include <hip/hip_runtime.h>
#include <math.h>

#define NB 8192
#define ND 512
#define NPROTO 16
#define NBLK 256                   // k_norm grid
#define TINV 14.285714285714286f   // 1/0.07
#define PW_BLOCKS 256
#define PL_BLOCKS 256
#define FIN_BLOCKS 64

typedef short short8 __attribute__((ext_vector_type(8)));
typedef float float4v __attribute__((ext_vector_type(4)));

__device__ __forceinline__ unsigned short f2bf(float f) {
  unsigned u = __builtin_bit_cast(unsigned, f);
  unsigned r = (u + 0x7FFFu + ((u >> 16) & 1u)) >> 16;
  return (unsigned short)r;
}
__device__ __forceinline__ float bflo(unsigned u) {
  return __builtin_bit_cast(float, u << 16);
}
__device__ __forceinline__ float bfhi(unsigned u) {
  return __builtin_bit_cast(float, u & 0xFFFF0000u);
}

// ---- K1: wave-per-row normalize + bf16 store + non-atomic partial sums ----
// d-axis stored PERMUTED (phys i=k*64+lane <- logical 4*lane+..); all consumers
// are dot products/norms over d -> permutation-invariant (shared physical order).
__global__ __launch_bounds__(512) void k_norm(
    const float* __restrict__ z, const float* __restrict__ attr,
    unsigned short* __restrict__ znb, float* __restrict__ partialSum,
    int* __restrict__ code, unsigned* __restrict__ doneCnt)
{
  __shared__ float acc[NPROTO * ND];   // 32 KB
  const int t = threadIdx.x, lane = t & 63, wid = t >> 6;
  for (int i = t; i < NPROTO * ND; i += 512) acc[i] = 0.f;
  if (blockIdx.x == 0 && t == 0) doneCnt[0] = 0u;   // re-arm finalize each replay
  __syncthreads();
  #pragma unroll
  for (int rr = 0; rr < 4; ++rr) {
    const int r = blockIdx.x * 32 + wid * 4 + rr;
    const float4* zr4 = (const float4*)(z + (size_t)r * ND);
    const float4 va = zr4[lane];
    const float4 vb = zr4[lane + 64];
    float v[8] = {va.x, va.y, va.z, va.w, vb.x, vb.y, vb.z, vb.w};
    float s = 0.f;
    #pragma unroll
    for (int k = 0; k < 8; ++k) s += v[k] * v[k];
    #pragma unroll
    for (int o = 32; o > 0; o >>= 1) s += __shfl_xor(s, o);
    const float inv = 1.f / fmaxf(sqrtf(s), 1e-12f);
    const float* a = attr + (size_t)r * 4;
    const int c = (a[0] > 0.5f ? 8 : 0) | (a[1] > 0.5f ? 4 : 0) |
                  (a[2] > 0.5f ? 2 : 0) | (a[3] > 0.5f ? 1 : 0);
    float* accRow = acc + c * ND;
    #pragma unroll
    for (int k = 0; k < 8; ++k) {
      const float zv = v[k] * inv;
      atomicAdd(&accRow[k * 64 + lane], zv);         // bank=lane%32: conflict-free
      znb[(size_t)r * ND + k * 64 + lane] = f2bf(zv);
    }
    if (lane == 0) code[r] = c;
  }
  __syncthreads();
  for (int i = t; i < NPROTO * ND; i += 512) {      // full overwrite: no pre-zero
    const int p = i >> 9, d = i & 511;
    partialSum[(size_t)((p << 8) | blockIdx.x) * ND + d] = acc[i];
  }
}

// ---- K1b: stage-1 reduce: 256 blocks, (p,c) sums 16 partials --------------
__global__ __launch_bounds__(256) void k_reduce1(
    const float* __restrict__ partialSum, float* __restrict__ partial2)
{
  const int t = threadIdx.x;
  const int p = blockIdx.x >> 4, c = blockIdx.x & 15;
  const float* base = partialSum + (size_t)(p * NBLK + c * 16) * ND;
  float s0 = 0.f, s1 = 0.f;
  #pragma unroll
  for (int k = 0; k < 16; ++k) {
    s0 += base[k * ND + t];
    s1 += base[k * ND + t + 256];
  }
  partial2[(size_t)(p * 16 + c) * ND + t] = s0;
  partial2[(size_t)(p * 16 + c) * ND + t + 256] = s1;
}

// ---- K2: 16 blocks: final reduce (32KB each) + normalize + validList ------
__global__ __launch_bounds__(512) void k_protonorm(
    const float* __restrict__ partial2, const int* __restrict__ code,
    float* __restrict__ protos, int* __restrict__ validList,
    int* __restrict__ validCnt)
{
  __shared__ float red[8];
  __shared__ int lcnt;
  const int t = threadIdx.x, lane = t & 63, wid = t >> 6;
  const int p = blockIdx.x;
  if (t == 0) lcnt = 0;
  __syncthreads();
  const float* base = partial2 + (size_t)p * 16 * ND;
  float s = 0.f;
  #pragma unroll
  for (int c = 0; c < 16; ++c)
    s += base[c * ND + t];
  float cl = 0.f;
  for (int r = t; r < NB; r += 512) {
    const int match = (code[r] == p) ? 1 : 0;
    cl += (float)match;
    if (p == NPROTO - 1 && match) {
      const int slot = atomicAdd(&lcnt, 1);
      validList[slot] = r;
    }
  }
  #pragma unroll
  for (int o = 32; o > 0; o >>= 1) cl += __shfl_xor(cl, o);
  if (lane == 0) red[wid] = cl;
  __syncthreads();
  const float cTot = red[0]+red[1]+red[2]+red[3]+red[4]+red[5]+red[6]+red[7];
  __syncthreads();
  const float mean = s / fmaxf(cTot, 1.f);
  float sq = mean * mean;
  #pragma unroll
  for (int o = 32; o > 0; o >>= 1) sq += __shfl_xor(sq, o);
  if (lane == 0) red[wid] = sq;
  __syncthreads();
  const float sum = red[0]+red[1]+red[2]+red[3]+red[4]+red[5]+red[6]+red[7];
  const float scale = (cTot > 0.f) ? 1.f / fmaxf(sqrtf(sum), 1e-12f) : 0.f;
  protos[p * ND + t] = mean * scale;
  if (p == NPROTO - 1 && t == 0) validCnt[0] = lcnt;
}

// ---- K3: fused {pairwise MFMA GEMM (512thr, 64x256 tile) | protoloss} -----
#define PLD (ND + 4)
#define SMEM_BYTES 41472
__global__ __launch_bounds__(512) void k_main(
    const unsigned short* __restrict__ znb, const float* __restrict__ protos,
    const int* __restrict__ code, const int* __restrict__ validList,
    const int* __restrict__ validCnt,
    float* __restrict__ partialAll, float* __restrict__ partialPos,
    float* __restrict__ plPart)
{
  __shared__ __align__(16) char smem[SMEM_BYTES];
  __shared__ float red3[8];
  const int t = threadIdx.x, lane = t & 63, wid = t >> 6;
  const int bi = blockIdx.x;
  if (bi < PW_BLOCKS) {
    // -------- pairwise: 8 waves (2i x 4j), tile 64i x 256j, K-chunk 64 ----
    unsigned short* aT = (unsigned short*)smem;             // 64x64, 8 KB
    unsigned short* bT = aT + 64 * 64;                      // 256x64, 32 KB
    int* rowIdx = (int*)(bT + 256 * 64);                    // 64
    unsigned char* aoSh = (unsigned char*)(rowIdx + 64);    // 256
    const int wv = wid >> 2, ww = wid & 3;
    const int m = validCnt[0];
    const int nIT = (m + 63) >> 6;
    const int items = nIT * 32;                             // 32 j-tiles of 256
    const int grp = lane >> 4, cl = lane & 15;
    for (int wi = bi; wi < items; wi += PW_BLOCKS) {
      const int i0 = (wi >> 5) * 64;
      const int jt = wi & 31;
      const int jb = jt * 256;
      __syncthreads();
      if (t < 64) rowIdx[t] = (i0 + t < m) ? validList[i0 + t] : -1;
      if (t < 256) aoSh[t] = (code[jb + t] == NPROTO - 1) ? 1 : 0;
      float4v acc[2][4];
      #pragma unroll
      for (int mi = 0; mi < 2; ++mi)
        #pragma unroll
        for (int nj = 0; nj < 4; ++nj) acc[mi][nj] = (float4v)(0.f);
      for (int kc = 0; kc < 8; ++kc) {
        const int k0 = kc * 64;
        __syncthreads();
        {  // stage A: 64 rows x 8 chunks = 512, 1/thread
          const int ia = t >> 3, kq = t & 7;
          const int ri = rowIdx[ia];
          const int srow = (ri < 0) ? 0 : ri;
          const uint4 v = *(const uint4*)(znb + (size_t)srow * ND + k0 + kq * 8);
          *(uint4*)((char*)aT + ia * 128 + ((kq * 16) ^ ((ia & 7) << 4))) = v;
        }
        #pragma unroll
        for (int h = 0; h < 4; ++h) {  // stage B: 256 rows x 8 chunks, 4/thread
          const int f = t + h * 512;
          const int j = f >> 3, kq = f & 7;
          const uint4 v = *(const uint4*)(znb + (size_t)(jb + j) * ND + k0 + kq * 8);
          *(uint4*)((char*)bT + j * 128 + ((kq * 16) ^ ((j & 7) << 4))) = v;
        }
        __syncthreads();
        #pragma unroll
        for (int ks = 0; ks < 2; ++ks) {
          const int kb = ks * 64 + grp * 16;
          short8 af[2], bf[4];
          #pragma unroll
          for (int mi = 0; mi < 2; ++mi) {
            const int rw = wv * 32 + mi * 16 + cl;
            af[mi] = *(const short8*)((char*)aT + rw * 128 + (kb ^ ((rw & 7) << 4)));
          }
          #pragma unroll
          for (int nj = 0; nj < 4; ++nj) {
            const int rw = ww * 64 + nj * 16 + cl;
            bf[nj] = *(const short8*)((char*)bT + rw * 128 + (kb ^ ((rw & 7) << 4)));
          }
          #pragma unroll
          for (int mi = 0; mi < 2; ++mi)
            #pragma unroll
            for (int nj = 0; nj < 4; ++nj)
              acc[mi][nj] = __builtin_amdgcn_mfma_f32_16x16x32_bf16(af[mi], bf[nj], acc[mi][nj], 0, 0, 0);
        }
      }
      // epilogue: exp, diag+pos masks, row sums, direct partial writes
      #pragma unroll
      for (int mi = 0; mi < 2; ++mi) {
        float sA[4] = {0.f, 0.f, 0.f, 0.f}, sP[4] = {0.f, 0.f, 0.f, 0.f};
        int ri[4];
        #pragma unroll
        for (int q = 0; q < 4; ++q) ri[q] = rowIdx[wv * 32 + mi * 16 + grp * 4 + q];
        #pragma unroll
        for (int nj = 0; nj < 4; ++nj) {
          const int jl = ww * 64 + nj * 16 + cl;
          const int jg = jb + jl;
          const float ao = aoSh[jl] ? 1.f : 0.f;
          #pragma unroll
          for (int q = 0; q < 4; ++q) {
            float e = __expf(acc[mi][nj][q] * TINV);
            e = (jg == ri[q]) ? 0.f : e;
            sA[q] += e;
            sP[q] += e * ao;
          }
        }
        #pragma unroll
        for (int q = 0; q < 4; ++q) {
          #pragma unroll
          for (int o = 1; o < 16; o <<= 1) {
            sA[q] += __shfl_xor(sA[q], o);
            sP[q] += __shfl_xor(sP[q], o);
          }
        }
        if (cl == 0) {
          const int slot0 = i0 + wv * 32 + mi * 16 + grp * 4;
          const int jt2 = jt * 4 + ww;                      // 0..127
          if (slot0 + 3 < m) {
            *(float4*)&partialAll[(size_t)jt2 * NB + slot0] =
                make_float4(sA[0], sA[1], sA[2], sA[3]);
            *(float4*)&partialPos[(size_t)jt2 * NB + slot0] =
                make_float4(sP[0], sP[1], sP[2], sP[3]);
          } else {
            #pragma unroll
            for (int q = 0; q < 4; ++q) {
              if (slot0 + q < m) {
                partialAll[(size_t)jt2 * NB + slot0 + q] = sA[q];
                partialPos[(size_t)jt2 * NB + slot0 + q] = sP[q];
              }
            }
          }
        }
      }
    }
  } else {
    // -------- protoloss: 256 blocks x 512 thr, 32 rows each ---------------
    float* pl = (float*)smem;                               // [16][PLD]
    const int pb = bi - PW_BLOCKS;
    for (int i = t; i < NPROTO * ND; i += 512)
      pl[(i >> 9) * PLD + (i & 511)] = protos[i];
    __syncthreads();
    const int p = lane & 15, grp = lane >> 4;
    float lacc = 0.f;
    #pragma unroll
    for (int rr = 0; rr < 4; ++rr) {
      const int r = pb * 32 + wid * 4 + rr;
      const uint4* zr = (const uint4*)(znb + (size_t)r * ND + grp * 128);
      const float* pbp = &pl[p * PLD + grp * 128];
      float s = 0.f;
      #pragma unroll
      for (int it = 0; it < 16; ++it) {
        const uint4 u = zr[it];
        const float4 p0 = *(const float4*)(pbp + it * 8);
        const float4 p1 = *(const float4*)(pbp + it * 8 + 4);
        s += bflo(u.x)*p0.x + bfhi(u.x)*p0.y + bflo(u.y)*p0.z + bfhi(u.y)*p0.w;
        s += bflo(u.z)*p1.x + bfhi(u.z)*p1.y + bflo(u.w)*p1.z + bfhi(u.w)*p1.w;
      }
      s += __shfl_xor(s, 16);
      s += __shfl_xor(s, 32);
      const float e = __expf(s * TINV);
      float alls = e;
      alls += __shfl_xor(alls, 1);
      alls += __shfl_xor(alls, 2);
      alls += __shfl_xor(alls, 4);
      alls += __shfl_xor(alls, 8);
      const int c = code[r];
      const float pos = __shfl(e, (lane & ~15) | c);
      if (lane == 0) lacc += -logf(pos / fmaxf(alls, 1e-8f) + 1e-8f);
    }
    if (lane == 0) red3[wid] = lacc;
    __syncthreads();
    if (t == 0)
      plPart[pb] = red3[0]+red3[1]+red3[2]+red3[3]+red3[4]+red3[5]+red3[6]+red3[7];
  }
}

// ---- K4: finalize v2 — 64 blocks, wave-per-slot coalesced column reduce,
//          completion-counter final combine (64-block scale: cheap) ---------
__global__ __launch_bounds__(512) void k_final(
    const float* __restrict__ partialAll, const float* __restrict__ partialPos,
    const float* __restrict__ plPart, const int* __restrict__ validCnt,
    float* __restrict__ blockLoss, unsigned* __restrict__ doneCnt,
    float* __restrict__ out)
{
  __shared__ float red[8], red2[8];
  __shared__ bool isLast;
  const int t = threadIdx.x, lane = t & 63, wid = t >> 6;
  const int bi = blockIdx.x;
  const int m = validCnt[0];
  const int nvalid = (m >= 2) ? m : 0;
  // each wave owns slot s; lanes cover k=0..127 in two strides (coalesced)
  float bl = 0.f;
  for (int s = bi * 8 + wid; s < nvalid; s += FIN_BLOCKS * 8) {
    float a = partialAll[(size_t)lane * NB + s] +
              partialAll[(size_t)(lane + 64) * NB + s];
    float p = partialPos[(size_t)lane * NB + s] +
              partialPos[(size_t)(lane + 64) * NB + s];
    #pragma unroll
    for (int o = 32; o > 0; o >>= 1) {
      a += __shfl_xor(a, o);
      p += __shfl_xor(p, o);
    }
    if (lane == 0) bl += -logf(p / (a + 1e-8f) + 1e-8f);
  }
  if (lane == 0) red[wid] = bl;
  __syncthreads();
  if (t == 0) {
    blockLoss[bi] = red[0]+red[1]+red[2]+red[3]+red[4]+red[5]+red[6]+red[7];
    __threadfence();
    const unsigned v = atomicAdd(doneCnt, 1u);
    isLast = (v == (unsigned)(FIN_BLOCKS - 1));
  }
  __syncthreads();
  if (!isLast) return;
  __threadfence();
  // last block: combine 64 blockLoss (atomic reads: same-dispatch writers)
  // + 256 plPart (prev-dispatch writers: plain reads safe)
  float s = (t < FIN_BLOCKS) ? atomicAdd(&blockLoss[t], 0.f) : 0.f;
  float pls = (t < PL_BLOCKS) ? plPart[t] : 0.f;
  #pragma unroll
  for (int o = 32; o > 0; o >>= 1) {
    s += __shfl_xor(s, o);
    pls += __shfl_xor(pls, o);
  }
  if (lane == 0) { red[wid] = s; red2[wid] = pls; }
  __syncthreads();
  if (t == 0) {
    const float total = red[0]+red[1]+red[2]+red[3]+red[4]+red[5]+red[6]+red[7];
    const float plTot = red2[0]+red2[1]+red2[2]+red2[3]+red2[4]+red2[5]+red2[6]+red2[7];
    const float proto = plTot / (float)NB;
    float loss = proto;
    if (nvalid > 0) loss = 0.7f * proto + 0.3f * (total / (float)nvalid);
    out[0] = loss;
  }
}

extern "C" void kernel_launch(void* const* d_in, const int* in_sizes, int n_in,
                              void* d_out, int out_size, void* d_ws, size_t ws_size,
                              hipStream_t stream) {
  const float* z = (const float*)d_in[0];
  const float* attr = (const float*)d_in[1];
  unsigned short* znb = (unsigned short*)d_ws;            // NB*ND bf16 (8 MB)
  float* partialSum = (float*)(znb + (size_t)NB * ND);    // [p][b][d] (8 MB)
  // overlay: partialSum is dead after k_reduce1/protonorm; k_main reuses it
  float* partialAll = partialSum;                         // [128][NB] (4 MB)
  float* partialPos = partialSum + (size_t)128 * NB;      // [128][NB] (4 MB)
  char* w = (char*)(partialSum + (size_t)NBLK * NPROTO * ND);
  float* partial2 = (float*)w;      w += (size_t)NPROTO * 16 * ND * 4;  // 512 KB
  int* validCnt = (int*)w;          w += 16;
  int* code = (int*)w;              w += NB * 4;
  int* validList = (int*)w;         w += NB * 4;
  float* protos = (float*)w;        w += NPROTO * ND * 4;
  float* plPart = (float*)w;        w += PL_BLOCKS * 4;
  float* blockLoss = (float*)w;     w += FIN_BLOCKS * 4;
  unsigned* doneCnt = (unsigned*)w; w += 16;
  k_norm<<<dim3(NBLK), dim3(512), 0, stream>>>(z, attr, znb, partialSum, code,
                                               doneCnt);
  k_reduce1<<<dim3(256), dim3(256), 0, stream>>>(partialSum, partial2);
  k_protonorm<<<dim3(NPROTO), dim3(512), 0, stream>>>(partial2, code, protos,
                                                      validList, validCnt);
  k_main<<<dim3(PW_BLOCKS + PL_BLOCKS), dim3(512), 0, stream>>>(
      znb, protos, code, validList, validCnt, partialAll, partialPos, plPart);
  k_final<<<dim3(FIN_BLOCKS), dim3(512), 0, stream>>>(
      partialAll, partialPos, plPart, validCnt, blockLoss, doneCnt,
      (float*)d_out);
}